// Round 8
// baseline (2286.528 us; speedup 1.0000x reference)
//
#include <hip/hip_runtime.h>

// ---------------------------------------------------------------------------
// QMixtralAttention: rmsnorm -> int8 quant -> QKV proj (EXACT i8 MFMA i32-acc,
// merged N=6144, BK=128 counted-vmcnt schedule) -> int4 KV quant -> RoPE ->
// causal GQA flash attention (swapped-operand bf16 MFMA, strip-paired balanced
// blocks) -> int8 -> O proj.
// ---------------------------------------------------------------------------

#define SQ   2048
#define HID  4096
#define NHEAD 32
#define HDIM 128
#define NKVH 8
#define KVD  1024   // NKVH*HDIM
#define QKVN 6144   // HID + 2*KVD

typedef __attribute__((ext_vector_type(8))) short          bh8;   // 8 x bf16 bits
typedef __attribute__((ext_vector_type(8))) unsigned short us8;
typedef __attribute__((ext_vector_type(4))) float          f4v;
typedef __attribute__((ext_vector_type(4))) int            i32x4; // i8 MFMA A/B/C

__device__ __forceinline__ unsigned short f2bf(float f) {
    unsigned u = __float_as_uint(f);
    u += 0x7fffu + ((u >> 16) & 1u);          // RNE
    return (unsigned short)(u >> 16);
}

__device__ __forceinline__ unsigned cvtpk_bf16(float a, float b) {
    unsigned r;
    asm("v_cvt_pk_bf16_f32 %0, %1, %2" : "=v"(r) : "v"(a), "v"(b));
    return r;
}

// async global -> LDS, 16B per lane (m97 pattern)
__device__ __forceinline__ void gl2lds16(const void* g, void* l) {
    __builtin_amdgcn_global_load_lds(
        (const __attribute__((address_space(1))) unsigned int*)g,
        (__attribute__((address_space(3))) unsigned int*)l, 16, 0, 0);
}

template<int N> __device__ __forceinline__ void vmc() {
    if constexpr (N == 0) asm volatile("s_waitcnt vmcnt(0)" ::: "memory");
    else if constexpr (N == 2) asm volatile("s_waitcnt vmcnt(2)" ::: "memory");
    else if constexpr (N == 4) asm volatile("s_waitcnt vmcnt(4)" ::: "memory");
    else if constexpr (N == 6) asm volatile("s_waitcnt vmcnt(6)" ::: "memory");
    else if constexpr (N == 8) asm volatile("s_waitcnt vmcnt(8)" ::: "memory");
}

// ---------------------------------------------------------------------------
// Shared per-row (4096-wide) symmetric int8 quant body -> packed int8 + scale.
// ---------------------------------------------------------------------------
__device__ __forceinline__ void rq_body(float v[16],
                                        char* __restrict__ dst,
                                        float* __restrict__ sout,
                                        float* red, int tid, int l, int wv)
{
    float am = 0.f;
#pragma unroll
    for (int i = 0; i < 16; i++) am = fmaxf(am, fabsf(v[i]));
#pragma unroll
    for (int o = 32; o >= 1; o >>= 1) am = fmaxf(am, __shfl_xor(am, o));
    if (l == 0) red[wv] = am;
    __syncthreads();
    am = fmaxf(fmaxf(red[0], red[1]), fmaxf(red[2], red[3]));
    float s = fmaxf(am / 127.0f, 1e-8f);
    if (tid == 0) *sout = s;
#pragma unroll
    for (int i = 0; i < 4; i++) {
        unsigned pk = 0;
#pragma unroll
        for (int j = 0; j < 4; j++) {
            float q = rintf(v[4*i+j] / s);         // true division: match jnp rounding
            q = fminf(fmaxf(q, -127.f), 127.f);
            pk |= ((unsigned)((int)q & 0xff)) << (8 * j);
        }
        ((unsigned*)dst)[i * 256 + tid] = pk;      // bytes i*1024 + tid*4
    }
}

// All 4 weight matrices (10240 rows) + rmsnorm'd hidden states (2048 rows)
// int8-quantized in ONE dispatch.
__global__ __launch_bounds__(256) void prequant(
    const float* __restrict__ Wq, const float* __restrict__ Wk,
    const float* __restrict__ Wv, const float* __restrict__ Wo,
    const float* __restrict__ X, const float* __restrict__ rw,
    char* __restrict__ wqkv, char* __restrict__ woq, char* __restrict__ xq,
    float* __restrict__ swqkv, float* __restrict__ swo, float* __restrict__ sx)
{
    int row = blockIdx.x;
    int tid = threadIdx.x;
    int l = tid & 63, wv = tid >> 6;
    const float* src; char* dst; float* sout; bool dorms = false;
    if (row < HID)            { src = Wq + (size_t)row * HID;                 dst = wqkv + (size_t)row * HID; sout = swqkv + row; }
    else if (row < HID + KVD) { src = Wk + (size_t)(row - HID) * HID;         dst = wqkv + (size_t)row * HID; sout = swqkv + row; }
    else if (row < QKVN)      { src = Wv + (size_t)(row - HID - KVD) * HID;   dst = wqkv + (size_t)row * HID; sout = swqkv + row; }
    else if (row < QKVN+HID)  { int r = row - QKVN; src = Wo + (size_t)r * HID; dst = woq + (size_t)r * HID;  sout = swo + r; }
    else { int r = row - QKVN - HID; src = X + (size_t)r * HID; dst = xq + (size_t)r * HID; sout = sx + r; dorms = true; }
    float v[16];
#pragma unroll
    for (int i = 0; i < 4; i++) {
        float4 f = ((const float4*)src)[i * 256 + tid];
        v[4*i+0] = f.x; v[4*i+1] = f.y; v[4*i+2] = f.z; v[4*i+3] = f.w;
    }
    __shared__ float red[4];
    if (dorms) {
        float ss = 0.f;
#pragma unroll
        for (int i = 0; i < 16; i++) ss += v[i] * v[i];
#pragma unroll
        for (int o = 32; o >= 1; o >>= 1) ss += __shfl_xor(ss, o);
        if (l == 0) red[wv] = ss;
        __syncthreads();
        float tot = red[0] + red[1] + red[2] + red[3];
        float rs = rsqrtf(tot * (1.0f / 4096.0f) + 1e-5f);
        __syncthreads();   // red reused below
#pragma unroll
        for (int i = 0; i < 4; i++) {
            float4 wf = ((const float4*)rw)[i * 256 + tid];
            v[4*i+0] = v[4*i+0] * rs * wf.x;
            v[4*i+1] = v[4*i+1] * rs * wf.y;
            v[4*i+2] = v[4*i+2] * rs * wf.z;
            v[4*i+3] = v[4*i+3] * rs * wf.w;
        }
    }
    rq_body(v, dst, sout, red, tid, l, wv);
}

// Per-row int8 quant, no rms (attn output)
__global__ __launch_bounds__(256) void rowquant_kernel(
    const float* __restrict__ X, char* __restrict__ Q, float* __restrict__ Sout)
{
    int row = blockIdx.x;
    int tid = threadIdx.x;
    int l = tid & 63, wv = tid >> 6;
    const float* xr = X + (size_t)row * 4096;
    float v[16];
#pragma unroll
    for (int i = 0; i < 4; i++) {
        float4 f = ((const float4*)xr)[i * 256 + tid];
        v[4*i+0] = f.x; v[4*i+1] = f.y; v[4*i+2] = f.z; v[4*i+3] = f.w;
    }
    __shared__ float red[4];
    rq_body(v, Q + (size_t)row * 4096, Sout + row, red, tid, l, wv);
}

// ---------------------------------------------------------------------------
// int8 GEMM (EXACT i32 accum): C[m][n] = sa[m]*sb[n] * sum_k A[m][k]*B[n][k].
// mfma_i32_16x16x64_i8, BM=128 x BN (384/256), BK=128, 8 waves (2M x 4N).
// Grid = exactly 256 blocks.  Counted-vmcnt phase schedule (unchanged r6).
// ---------------------------------------------------------------------------
template<int BN>
__global__ __launch_bounds__(512, 1) void gemm128i8(
    const char* __restrict__ A, const char* __restrict__ B,
    const float* __restrict__ sa, const float* __restrict__ sb,
    float* __restrict__ C, int M, int N, int K, int NBM)
{
    constexpr int NQ  = BN / 128;
    constexpr int BSZ = BN * 128;              // bytes per B buffer
    __shared__ char As[2 * 16384];             // 2 buf x 128 rows x 128 B
    __shared__ char Bs[2 * BSZ];
    int tid = threadIdx.x;
    int l = tid & 63, wid = tid >> 6;
    int wr = wid >> 2, wc = wid & 3;           // 2M x 4N waves
    int g = l >> 4, c = l & 15;
    int wg = blockIdx.x;
    int cpx = (int)gridDim.x >> 3;             // grid == 256, multiple of 8
    int swz = (wg & 7) * cpx + (wg >> 3);
    int bm = swz % NBM, bn = swz / NBM;
    const char* Ab = A + (size_t)bm * 128 * K;
    const char* Bb = B + (size_t)bn * BN * K;

    auto stageA = [&](int buf, int tt) {
#pragma unroll
        for (int r = 0; r < 2; r++) {
            int e = (r * 512 + tid) * 16;      // 0..16383
            int row = e >> 7, chunk = (e >> 4) & 7;
            gl2lds16(Ab + (size_t)row * K + tt * 128 + ((chunk ^ (row & 7)) << 4),
                     As + buf * 16384 + e);
        }
    };
    auto stageB = [&](int buf, int u, int tt) {
#pragma unroll
        for (int r = 0; r < 2; r++) {
            int e = (r * 512 + tid) * 16;
            int row = e >> 7, chunk = (e >> 4) & 7;
            gl2lds16(Bb + (size_t)(u * 128 + row) * K + tt * 128 + ((chunk ^ (row & 7)) << 4),
                     Bs + buf * BSZ + u * 16384 + e);
        }
    };
    i32x4 af[4][2];
    auto LDA = [&](int buf) {
#pragma unroll
        for (int fm = 0; fm < 4; fm++)
#pragma unroll
            for (int kk = 0; kk < 2; kk++) {
                int row = wr * 64 + fm * 16 + c;
                af[fm][kk] = *(const i32x4*)(As + buf * 16384 + row * 128 +
                                             (((kk * 4 + g) ^ (row & 7)) << 4));
            }
    };

    stageA(0, 0);
#pragma unroll
    for (int u = 0; u < NQ; u++) stageB(0, u, 0);

    i32x4 acc[4][2 * NQ] = {};
    int nt = K >> 7;
    for (int t = 0; t < nt; t++) {
        int buf = t & 1;
        bool last = (t == nt - 1);
#pragma unroll
        for (int nq = 0; nq < NQ; nq++) {
            if (last) { if (nq == 0) vmc<0>(); }
            else if (nq == 0) vmc<2 * (NQ - 1)>();
            else vmc<2 * NQ>();
            asm volatile("s_barrier" ::: "memory");
            if (!last) {
                if (nq == 0) { stageA(buf ^ 1, t + 1); stageB(buf ^ 1, 0, t + 1); }
                else stageB(buf ^ 1, nq, t + 1);
            }
            if (nq == 0) LDA(buf);
            i32x4 bf[2][2];
#pragma unroll
            for (int fn = 0; fn < 2; fn++)
#pragma unroll
                for (int kk = 0; kk < 2; kk++) {
                    int rowu = wc * 32 + fn * 16 + c;   // within unit nq
                    bf[fn][kk] = *(const i32x4*)(Bs + buf * BSZ + nq * 16384 +
                                                 rowu * 128 +
                                                 (((kk * 4 + g) ^ (rowu & 7)) << 4));
                }
            asm volatile("s_waitcnt lgkmcnt(0)" ::: "memory");
            __builtin_amdgcn_sched_barrier(0);
            __builtin_amdgcn_s_setprio(1);
#pragma unroll
            for (int kk = 0; kk < 2; kk++)
#pragma unroll
                for (int fm = 0; fm < 4; fm++)
#pragma unroll
                    for (int fn = 0; fn < 2; fn++)
                        acc[fm][nq * 2 + fn] = __builtin_amdgcn_mfma_i32_16x16x64_i8(
                            af[fm][kk], bf[fn][kk], acc[fm][nq * 2 + fn], 0, 0, 0);
            __builtin_amdgcn_s_setprio(0);
        }
    }
#pragma unroll
    for (int fm = 0; fm < 4; fm++)
#pragma unroll
        for (int j = 0; j < 4; j++) {
            int row = bm * 128 + wr * 64 + fm * 16 + g * 4 + j;
            float sr = sa[row];
#pragma unroll
            for (int q = 0; q < 2 * NQ; q++) {
                int col = bn * BN + (q >> 1) * 128 + wc * 32 + (q & 1) * 16 + c;
                C[(size_t)row * N + col] = (float)acc[fm][q][j] * sr * sb[col];
            }
        }
}

// ---------------------------------------------------------------------------
// Merged post-GEMM kernel: blocks [0,256) = V int4 quant + transpose;
// blocks [256,..) = K int4-quant+RoPE waves then Q RoPE waves.
// ---------------------------------------------------------------------------
__global__ __launch_bounds__(256) void postq(
    const float* __restrict__ QKVf, const int* __restrict__ pos,
    unsigned short* __restrict__ Qbo, unsigned short* __restrict__ Kbo,
    unsigned short* __restrict__ Vbt)
{
    __shared__ unsigned short T[64][136];
    int bid = blockIdx.x;
    if (bid < 256) {                        // ---- V quant + transpose ----
        int t0 = (bid & 31) * 64;
        int kvh = bid >> 5;
        int tid = threadIdx.x;
        int r = tid >> 2, q4 = tid & 3;
        const float* gp = QKVf + (size_t)(t0 + r) * QKVN + (HID + KVD) + kvh * 128 + q4 * 32;
        float v[32];
#pragma unroll
        for (int i = 0; i < 8; i++) {
            float4 f = ((const float4*)gp)[i];
            v[4*i+0] = f.x; v[4*i+1] = f.y; v[4*i+2] = f.z; v[4*i+3] = f.w;
        }
        float mn = v[0], mx = v[0];
#pragma unroll
        for (int i = 1; i < 32; i++) { mn = fminf(mn, v[i]); mx = fmaxf(mx, v[i]); }
        mn = fminf(mn, __shfl_xor(mn, 1)); mx = fmaxf(mx, __shfl_xor(mx, 1));
        mn = fminf(mn, __shfl_xor(mn, 2)); mx = fmaxf(mx, __shfl_xor(mx, 2));
        float sc = fmaxf((mx - mn) / 15.0f, 1e-8f);
#pragma unroll
        for (int i = 0; i < 32; i++) {
            float q = fminf(fmaxf(rintf((v[i] - mn) / sc), 0.f), 15.f);
            T[r][q4 * 32 + i] = f2bf(q * sc + mn);
        }
        __syncthreads();
        int d = tid >> 1, hf = tid & 1;
#pragma unroll
        for (int b = 0; b < 4; b++) {
            us8 o;
#pragma unroll
            for (int j = 0; j < 8; j++) o[j] = T[hf * 32 + b * 8 + j][d];
            *(us8*)(Vbt + (size_t)(kvh * 128 + d) * SQ + t0 + hf * 32 + b * 8) = o;
        }
        return;
    }
    int wid = (bid - 256) * 4 + (threadIdx.x >> 6);
    int l = threadIdx.x & 63;
    float fr = exp2f(-(float)l * 0.3114307588956902f);   // log2(1e6)/64
    if (wid < SQ * NKVH) {                  // ---- K int4 quant + RoPE ----
        int t = wid >> 3, kvh = wid & 7;
        const float* gp = QKVf + (size_t)t * QKVN + HID + kvh * 128;
        float x1 = gp[l], x2 = gp[l + 64];
        float mn = fminf(x1, x2), mx = fmaxf(x1, x2);
#pragma unroll
        for (int o = 32; o >= 1; o >>= 1) {
            mn = fminf(mn, __shfl_xor(mn, o));
            mx = fmaxf(mx, __shfl_xor(mx, o));
        }
        float sc = fmaxf((mx - mn) / 15.0f, 1e-8f);
        float q1 = fminf(fmaxf(rintf((x1 - mn) / sc), 0.f), 15.f);
        float q2 = fminf(fmaxf(rintf((x2 - mn) / sc), 0.f), 15.f);
        x1 = q1 * sc + mn;
        x2 = q2 * sc + mn;
        float ang = (float)pos[t] * fr;
        float cs = cosf(ang), sn = sinf(ang);
        unsigned short* op = Kbo + (size_t)t * KVD + kvh * 128;
        op[l]      = f2bf(x1 * cs - x2 * sn);
        op[l + 64] = f2bf(x2 * cs + x1 * sn);
    } else {                                // ---- Q RoPE (pre-scaled) ----
        const float QSCL = (float)(0.08838834764831845 * 1.4426950408889634);
        int w2 = wid - SQ * NKVH;
        int t = w2 >> 5, h = w2 & 31;
        const float* gp = QKVf + (size_t)t * QKVN + h * 128;
        float x1 = gp[l], x2 = gp[l + 64];
        float ang = (float)pos[t] * fr;
        float cs = cosf(ang), sn = sinf(ang);
        unsigned short* op = Qbo + (size_t)t * HID + h * 128;
        op[l]      = f2bf((x1 * cs - x2 * sn) * QSCL);
        op[l + 64] = f2bf((x2 * cs + x1 * sn) * QSCL);
    }
}

// ---------------------------------------------------------------------------
// Causal GQA flash attention, swapped-operand MFMA, STRIP-PAIRED blocks.
// Block (h, j) handles q-strips j (64 rows, group A) and 31-j (group B):
// every block = exactly 33 MFMA group-steps (kv-tiles: A needs j+1, B 32-j).
// 4 waves x 16 rows per strip.  K DMA double-buffered LDS; V^T reg-staged.
// Shared K/V fragment reads feed both groups while A is active (t <= j).
// ---------------------------------------------------------------------------
__global__ __launch_bounds__(256, 2) void attn_kernel(
    const unsigned short* __restrict__ Qb, const unsigned short* __restrict__ Kb,
    const unsigned short* __restrict__ Vbt, float* __restrict__ AO)
{
    int h = blockIdx.x;
    int j = blockIdx.y;                            // strips j and 31-j
    int kvh = h >> 2;                              // NREP=4, consecutive repeat
    int tid = threadIdx.x;
    int l = tid & 63, w = tid >> 6;
    int g = l >> 4, c = l & 15;
    __shared__ unsigned short Ks[2 * 8192];        // 2 x (64 keys x 128 d), swz
    __shared__ unsigned short Vt[128 * 64];        // V^T tile, chunk^(row&7) swz
    __shared__ unsigned short Plds[4][2][16][72];  // per-wave P rows, 2 groups
    int rowA = j * 64 + w * 16 + c;                // group A q-row (strip j)
    int rowB = (31 - j) * 64 + w * 16 + c;         // group B q-row (strip 31-j)
    int NT = 32 - j;                               // kv tiles for group B

    auto stageK = [&](int buf, int kv0) {
#pragma unroll
        for (int i = 0; i < 4; i++) {
            int e = (i * 256 + tid) * 8;           // 0..8191
            int row = e >> 7, chunk = (e >> 3) & 15;
            gl2lds16(Kb + (size_t)(kv0 + row) * KVD + kvh * 128 + ((chunk ^ (row & 15)) << 3),
                     Ks + buf * 8192 + e);
        }
    };
    us8 vreg[4];
    auto stageV = [&](int kv0) {
#pragma unroll
        for (int i = 0; i < 4; i++) {
            int e = (i * 256 + tid) * 8;
            int r = e >> 6, cc = e & 63;
            vreg[i] = *(const us8*)(Vbt + (size_t)(kvh * 128 + r) * SQ + kv0 + cc);
        }
    };
    auto writeV = [&]() {
#pragma unroll
        for (int i = 0; i < 4; i++) {
            int e = (i * 256 + tid) * 8;
            int rv = e >> 6, chv = (e >> 3) & 7;
            *(us8*)(Vt + rv * 64 + ((chv ^ (rv & 7)) << 3)) = vreg[i];
        }
    };

    stageK(0, 0);
    stageV(0);

    bh8 qfA[4], qfB[4];
    {
        const unsigned short* qa = Qb + (size_t)rowA * HID + h * 128;
        const unsigned short* qp = Qb + (size_t)rowB * HID + h * 128;
#pragma unroll
        for (int kk = 0; kk < 4; kk++) {
            qfA[kk] = *(const bh8*)(qa + kk * 32 + g * 8);
            qfB[kk] = *(const bh8*)(qp + kk * 32 + g * 8);
        }
    }
    writeV();
    asm volatile("s_waitcnt vmcnt(0)" ::: "memory");
    __syncthreads();

    f4v accA[8] = {}, accB[8] = {};
    float mrunA = -1e30f, lrunA = 0.f, mrunB = -1e30f, lrunB = 0.f;

    auto softmax = [&](f4v (&sf)[4], float& mrun, float& lrun, f4v (&acc)[8],
                       unsigned short* PW) {
        float pmax = sf[0][0];
#pragma unroll
        for (int n = 0; n < 4; n++)
#pragma unroll
            for (int jj = 0; jj < 4; jj++) pmax = fmaxf(pmax, sf[n][jj]);
        pmax = fmaxf(pmax, __shfl_xor(pmax, 16));
        pmax = fmaxf(pmax, __shfl_xor(pmax, 32));
        if (__any(pmax - mrun > 8.0f)) {           // defer-max (T13)
            float mnew = fmaxf(mrun, pmax);
            float alpha = exp2f(mrun - mnew);
            mrun = mnew;
            lrun *= alpha;
#pragma unroll
            for (int n = 0; n < 8; n++) acc[n] *= alpha;
        }
        float rsum = 0.f;
#pragma unroll
        for (int n = 0; n < 4; n++)
#pragma unroll
            for (int jj = 0; jj < 4; jj++) {
                float pv = exp2f(sf[n][jj] - mrun);
                sf[n][jj] = pv;
                rsum += pv;
            }
        rsum += __shfl_xor(rsum, 16);
        rsum += __shfl_xor(rsum, 32);
        lrun += rsum;
#pragma unroll
        for (int n = 0; n < 4; n++) {
            uint2 u;
            u.x = cvtpk_bf16(sf[n][0], sf[n][1]);
            u.y = cvtpk_bf16(sf[n][2], sf[n][3]);
            *(uint2*)(PW + c * 72 + n * 16 + g * 4) = u;
        }
    };

    for (int t = 0; t < NT; t++) {
        int kv0 = t * 64;
        int buf = t & 1;
        bool dA = (t <= j);                        // group A still active
        if (t + 1 < NT) { stageK(buf ^ 1, kv0 + 64); stageV(kv0 + 64); }
        f4v sfA[4] = {}, sfB[4];
        __builtin_amdgcn_s_setprio(1);
#pragma unroll
        for (int n = 0; n < 4; n++) {
            f4v aA = {}, aB = {};
            int rowk = n * 16 + c;
#pragma unroll
            for (int kk = 0; kk < 4; kk++) {
                bh8 kf = *(const bh8*)(Ks + buf * 8192 + rowk * 128 +
                                       (((kk * 4 + g) ^ (rowk & 15)) << 3));
                aB = __builtin_amdgcn_mfma_f32_16x16x32_bf16(kf, qfB[kk], aB, 0, 0, 0);
                if (dA) aA = __builtin_amdgcn_mfma_f32_16x16x32_bf16(kf, qfA[kk], aA, 0, 0, 0);
            }
            sfB[n] = aB; sfA[n] = aA;
        }
        __builtin_amdgcn_s_setprio(0);
        if (t == NT - 1) {                         // group B diagonal tile
#pragma unroll
            for (int n = 0; n < 4; n++)
#pragma unroll
                for (int jj = 0; jj < 4; jj++)
                    if (kv0 + n * 16 + g * 4 + jj > rowB) sfB[n][jj] = -1e30f;
        }
        if (dA && t == j) {                        // group A diagonal tile
#pragma unroll
            for (int n = 0; n < 4; n++)
#pragma unroll
                for (int jj = 0; jj < 4; jj++)
                    if (kv0 + n * 16 + g * 4 + jj > rowA) sfA[n][jj] = -1e30f;
        }
        softmax(sfB, mrunB, lrunB, accB, &Plds[w][1][0][0]);
        if (dA) softmax(sfA, mrunA, lrunA, accA, &Plds[w][0][0][0]);
        __builtin_amdgcn_s_setprio(1);
#pragma unroll
        for (int kk = 0; kk < 2; kk++) {
            bh8 pbB = *(const bh8*)(&Plds[w][1][c][kk * 32 + g * 8]);
            bh8 pbA = *(const bh8*)(&Plds[w][0][c][kk * 32 + g * 8]);
#pragma unroll
            for (int n = 0; n < 8; n++) {
                int rowv = n * 16 + c;
                bh8 vf = *(const bh8*)(Vt + rowv * 64 + (((kk * 4 + g) ^ (rowv & 7)) << 3));
                accB[n] = __builtin_amdgcn_mfma_f32_16x16x32_bf16(vf, pbB, accB[n], 0, 0, 0);
                if (dA) accA[n] = __builtin_amdgcn_mfma_f32_16x16x32_bf16(vf, pbA, accA[n], 0, 0, 0);
            }
        }
        __builtin_amdgcn_s_setprio(0);
        if (t + 1 < NT) {
            __syncthreads();
            writeV();
            asm volatile("s_waitcnt vmcnt(0)" ::: "memory");
            __syncthreads();
        }
    }
    float invA = 1.0f / lrunA, invB = 1.0f / lrunB;
#pragma unroll
    for (int n = 0; n < 8; n++) {
        f4v oA = accA[n] * invA;
        f4v oB = accB[n] * invB;
        *(f4v*)(AO + (size_t)rowA * HID + h * 128 + n * 16 + g * 4) = oA;
        *(f4v*)(AO + (size_t)rowB * HID + h * 128 + n * 16 + g * 4) = oB;
    }
}

// ---------------------------------------------------------------------------
extern "C" void kernel_launch(void* const* d_in, const int* in_sizes, int n_in,
                              void* d_out, int out_size, void* d_ws, size_t ws_size,
                              hipStream_t stream)
{
    const float* x   = (const float*)d_in[0];
    const int*   pos = (const int*)d_in[1];
    const float* rw  = (const float*)d_in[2];
    const float* Wq  = (const float*)d_in[3];
    const float* Wk  = (const float*)d_in[4];
    const float* Wv  = (const float*)d_in[5];
    const float* Wo  = (const float*)d_in[6];
    float* out = (float*)d_out;

    char* p = (char*)d_ws;
    auto alloc = [&](size_t bytes) -> void* {
        void* r = (void*)p;
        p += (bytes + 255) & ~(size_t)255;
        return r;
    };
    char*           xq    = (char*)alloc((size_t)SQ * HID);
    float*          sx    = (float*)alloc(SQ * 4);
    char*           wqkv  = (char*)alloc((size_t)QKVN * HID);
    char*           woq   = (char*)alloc((size_t)HID * HID);
    float*          swqkv = (float*)alloc(QKVN * 4);
    float*          swo   = (float*)alloc(HID * 4);
    float*          QKVf  = (float*)alloc((size_t)SQ * QKVN * 4);  // reused: AO, attq
    unsigned short* Qb    = (unsigned short*)alloc((size_t)SQ * HID * 2);
    unsigned short* Kb    = (unsigned short*)alloc((size_t)SQ * KVD * 2);
    unsigned short* Vbt   = (unsigned short*)alloc((size_t)SQ * KVD * 2);
    float*          sa    = (float*)alloc(SQ * 4);

    size_t need = (size_t)(p - (char*)d_ws);
    if (ws_size < need) {
        // sentinel: absmax ~3.4e38 tells us ws was too small
        hipMemsetAsync(d_out, 0x7f, 4, stream);
        return;
    }
    float*          AO   = QKVf;                                   // QKV consumed before attn
    char*           attq = (char*)(QKVf + (size_t)SQ * HID);
    // 1) weights + rmsnorm'd hidden states int8-quantized in one dispatch
    prequant<<<QKVN + HID + SQ, 256, 0, stream>>>(
        Wq, Wk, Wv, Wo, x, rw, wqkv, woq, xq, swqkv, swo, sx);
    // 2) merged QKV projection: EXACT i8 MFMA; BM=128 BN=384 -> 256 blocks
    gemm128i8<384><<<dim3((SQ / 128) * (QKVN / 384)), 512, 0, stream>>>(
        xq, wqkv, sx, swqkv, QKVf, SQ, QKVN, HID, SQ / 128);
    // 3) V quant+transpose, K quant+RoPE, Q RoPE in one dispatch
    postq<<<256 + (SQ * NKVH + SQ * NHEAD) / 4, 256, 0, stream>>>(
        QKVf, pos, Qb, Kb, Vbt);
    // 4) causal GQA flash attention (strip-paired balanced blocks)
    attn_kernel<<<dim3(NHEAD, 16), 256, 0, stream>>>(Qb, Kb, Vbt, AO);
    // 5) per-token int8 quant of attention output + O projection
    rowquant_kernel<<<SQ, 256, 0, stream>>>(AO, attq, sa);
    gemm128i8<256><<<dim3((SQ / 128) * (HID / 256)), 512, 0, stream>>>(
        attq, woq, sa, swo, out, SQ, HID, HID, SQ / 128);
}

// Round 9
// 244.000 us; speedup vs baseline: 9.3710x; 9.3710x over previous
//
#include <hip/hip_runtime.h>

// ---------------------------------------------------------------------------
// QMixtralAttention: rmsnorm -> int8 quant -> QKV proj (EXACT i8 MFMA i32-acc,
// merged N=6144, BK=128 counted-vmcnt schedule) -> int4 KV quant -> RoPE ->
// causal GQA flash attention (swapped-operand bf16 MFMA, strip-paired blocks,
// SPLIT loops: dual-group then single-group, no conditionals) -> int8 -> O proj.
// ---------------------------------------------------------------------------

#define SQ   2048
#define HID  4096
#define NHEAD 32
#define HDIM 128
#define NKVH 8
#define KVD  1024   // NKVH*HDIM
#define QKVN 6144   // HID + 2*KVD

typedef __attribute__((ext_vector_type(8))) short          bh8;   // 8 x bf16 bits
typedef __attribute__((ext_vector_type(8))) unsigned short us8;
typedef __attribute__((ext_vector_type(4))) float          f4v;
typedef __attribute__((ext_vector_type(4))) int            i32x4; // i8 MFMA A/B/C

__device__ __forceinline__ unsigned short f2bf(float f) {
    unsigned u = __float_as_uint(f);
    u += 0x7fffu + ((u >> 16) & 1u);          // RNE
    return (unsigned short)(u >> 16);
}

__device__ __forceinline__ unsigned cvtpk_bf16(float a, float b) {
    unsigned r;
    asm("v_cvt_pk_bf16_f32 %0, %1, %2" : "=v"(r) : "v"(a), "v"(b));
    return r;
}

// async global -> LDS, 16B per lane (m97 pattern)
__device__ __forceinline__ void gl2lds16(const void* g, void* l) {
    __builtin_amdgcn_global_load_lds(
        (const __attribute__((address_space(1))) unsigned int*)g,
        (__attribute__((address_space(3))) unsigned int*)l, 16, 0, 0);
}

template<int N> __device__ __forceinline__ void vmc() {
    if constexpr (N == 0) asm volatile("s_waitcnt vmcnt(0)" ::: "memory");
    else if constexpr (N == 2) asm volatile("s_waitcnt vmcnt(2)" ::: "memory");
    else if constexpr (N == 4) asm volatile("s_waitcnt vmcnt(4)" ::: "memory");
    else if constexpr (N == 6) asm volatile("s_waitcnt vmcnt(6)" ::: "memory");
    else if constexpr (N == 8) asm volatile("s_waitcnt vmcnt(8)" ::: "memory");
}

// ---------------------------------------------------------------------------
// Shared per-row (4096-wide) symmetric int8 quant body -> packed int8 + scale.
// ---------------------------------------------------------------------------
__device__ __forceinline__ void rq_body(float v[16],
                                        char* __restrict__ dst,
                                        float* __restrict__ sout,
                                        float* red, int tid, int l, int wv)
{
    float am = 0.f;
#pragma unroll
    for (int i = 0; i < 16; i++) am = fmaxf(am, fabsf(v[i]));
#pragma unroll
    for (int o = 32; o >= 1; o >>= 1) am = fmaxf(am, __shfl_xor(am, o));
    if (l == 0) red[wv] = am;
    __syncthreads();
    am = fmaxf(fmaxf(red[0], red[1]), fmaxf(red[2], red[3]));
    float s = fmaxf(am / 127.0f, 1e-8f);
    if (tid == 0) *sout = s;
#pragma unroll
    for (int i = 0; i < 4; i++) {
        unsigned pk = 0;
#pragma unroll
        for (int j = 0; j < 4; j++) {
            float q = rintf(v[4*i+j] / s);         // true division: match jnp rounding
            q = fminf(fmaxf(q, -127.f), 127.f);
            pk |= ((unsigned)((int)q & 0xff)) << (8 * j);
        }
        ((unsigned*)dst)[i * 256 + tid] = pk;      // bytes i*1024 + tid*4
    }
}

// All 4 weight matrices (10240 rows) + rmsnorm'd hidden states (2048 rows)
// int8-quantized in ONE dispatch.
__global__ __launch_bounds__(256) void prequant(
    const float* __restrict__ Wq, const float* __restrict__ Wk,
    const float* __restrict__ Wv, const float* __restrict__ Wo,
    const float* __restrict__ X, const float* __restrict__ rw,
    char* __restrict__ wqkv, char* __restrict__ woq, char* __restrict__ xq,
    float* __restrict__ swqkv, float* __restrict__ swo, float* __restrict__ sx)
{
    int row = blockIdx.x;
    int tid = threadIdx.x;
    int l = tid & 63, wv = tid >> 6;
    const float* src; char* dst; float* sout; bool dorms = false;
    if (row < HID)            { src = Wq + (size_t)row * HID;                 dst = wqkv + (size_t)row * HID; sout = swqkv + row; }
    else if (row < HID + KVD) { src = Wk + (size_t)(row - HID) * HID;         dst = wqkv + (size_t)row * HID; sout = swqkv + row; }
    else if (row < QKVN)      { src = Wv + (size_t)(row - HID - KVD) * HID;   dst = wqkv + (size_t)row * HID; sout = swqkv + row; }
    else if (row < QKVN+HID)  { int r = row - QKVN; src = Wo + (size_t)r * HID; dst = woq + (size_t)r * HID;  sout = swo + r; }
    else { int r = row - QKVN - HID; src = X + (size_t)r * HID; dst = xq + (size_t)r * HID; sout = sx + r; dorms = true; }
    float v[16];
#pragma unroll
    for (int i = 0; i < 4; i++) {
        float4 f = ((const float4*)src)[i * 256 + tid];
        v[4*i+0] = f.x; v[4*i+1] = f.y; v[4*i+2] = f.z; v[4*i+3] = f.w;
    }
    __shared__ float red[4];
    if (dorms) {
        float ss = 0.f;
#pragma unroll
        for (int i = 0; i < 16; i++) ss += v[i] * v[i];
#pragma unroll
        for (int o = 32; o >= 1; o >>= 1) ss += __shfl_xor(ss, o);
        if (l == 0) red[wv] = ss;
        __syncthreads();
        float tot = red[0] + red[1] + red[2] + red[3];
        float rs = rsqrtf(tot * (1.0f / 4096.0f) + 1e-5f);
        __syncthreads();   // red reused below
#pragma unroll
        for (int i = 0; i < 4; i++) {
            float4 wf = ((const float4*)rw)[i * 256 + tid];
            v[4*i+0] = v[4*i+0] * rs * wf.x;
            v[4*i+1] = v[4*i+1] * rs * wf.y;
            v[4*i+2] = v[4*i+2] * rs * wf.z;
            v[4*i+3] = v[4*i+3] * rs * wf.w;
        }
    }
    rq_body(v, dst, sout, red, tid, l, wv);
}

// Per-row int8 quant, no rms (attn output)
__global__ __launch_bounds__(256) void rowquant_kernel(
    const float* __restrict__ X, char* __restrict__ Q, float* __restrict__ Sout)
{
    int row = blockIdx.x;
    int tid = threadIdx.x;
    int l = tid & 63, wv = tid >> 6;
    const float* xr = X + (size_t)row * 4096;
    float v[16];
#pragma unroll
    for (int i = 0; i < 4; i++) {
        float4 f = ((const float4*)xr)[i * 256 + tid];
        v[4*i+0] = f.x; v[4*i+1] = f.y; v[4*i+2] = f.z; v[4*i+3] = f.w;
    }
    __shared__ float red[4];
    rq_body(v, Q + (size_t)row * 4096, Sout + row, red, tid, l, wv);
}

// ---------------------------------------------------------------------------
// int8 GEMM (EXACT i32 accum): C[m][n] = sa[m]*sb[n] * sum_k A[m][k]*B[n][k].
// mfma_i32_16x16x64_i8, BM=128 x BN (384/256), BK=128, 8 waves (2M x 4N).
// Grid = exactly 256 blocks.  Counted-vmcnt phase schedule (unchanged r6).
// ---------------------------------------------------------------------------
template<int BN>
__global__ __launch_bounds__(512, 1) void gemm128i8(
    const char* __restrict__ A, const char* __restrict__ B,
    const float* __restrict__ sa, const float* __restrict__ sb,
    float* __restrict__ C, int M, int N, int K, int NBM)
{
    constexpr int NQ  = BN / 128;
    constexpr int BSZ = BN * 128;              // bytes per B buffer
    __shared__ char As[2 * 16384];             // 2 buf x 128 rows x 128 B
    __shared__ char Bs[2 * BSZ];
    int tid = threadIdx.x;
    int l = tid & 63, wid = tid >> 6;
    int wr = wid >> 2, wc = wid & 3;           // 2M x 4N waves
    int g = l >> 4, c = l & 15;
    int wg = blockIdx.x;
    int cpx = (int)gridDim.x >> 3;             // grid == 256, multiple of 8
    int swz = (wg & 7) * cpx + (wg >> 3);
    int bm = swz % NBM, bn = swz / NBM;
    const char* Ab = A + (size_t)bm * 128 * K;
    const char* Bb = B + (size_t)bn * BN * K;

    auto stageA = [&](int buf, int tt) {
#pragma unroll
        for (int r = 0; r < 2; r++) {
            int e = (r * 512 + tid) * 16;      // 0..16383
            int row = e >> 7, chunk = (e >> 4) & 7;
            gl2lds16(Ab + (size_t)row * K + tt * 128 + ((chunk ^ (row & 7)) << 4),
                     As + buf * 16384 + e);
        }
    };
    auto stageB = [&](int buf, int u, int tt) {
#pragma unroll
        for (int r = 0; r < 2; r++) {
            int e = (r * 512 + tid) * 16;
            int row = e >> 7, chunk = (e >> 4) & 7;
            gl2lds16(Bb + (size_t)(u * 128 + row) * K + tt * 128 + ((chunk ^ (row & 7)) << 4),
                     Bs + buf * BSZ + u * 16384 + e);
        }
    };
    i32x4 af[4][2];
    auto LDA = [&](int buf) {
#pragma unroll
        for (int fm = 0; fm < 4; fm++)
#pragma unroll
            for (int kk = 0; kk < 2; kk++) {
                int row = wr * 64 + fm * 16 + c;
                af[fm][kk] = *(const i32x4*)(As + buf * 16384 + row * 128 +
                                             (((kk * 4 + g) ^ (row & 7)) << 4));
            }
    };

    stageA(0, 0);
#pragma unroll
    for (int u = 0; u < NQ; u++) stageB(0, u, 0);

    i32x4 acc[4][2 * NQ] = {};
    int nt = K >> 7;
    for (int t = 0; t < nt; t++) {
        int buf = t & 1;
        bool last = (t == nt - 1);
#pragma unroll
        for (int nq = 0; nq < NQ; nq++) {
            if (last) { if (nq == 0) vmc<0>(); }
            else if (nq == 0) vmc<2 * (NQ - 1)>();
            else vmc<2 * NQ>();
            asm volatile("s_barrier" ::: "memory");
            if (!last) {
                if (nq == 0) { stageA(buf ^ 1, t + 1); stageB(buf ^ 1, 0, t + 1); }
                else stageB(buf ^ 1, nq, t + 1);
            }
            if (nq == 0) LDA(buf);
            i32x4 bf[2][2];
#pragma unroll
            for (int fn = 0; fn < 2; fn++)
#pragma unroll
                for (int kk = 0; kk < 2; kk++) {
                    int rowu = wc * 32 + fn * 16 + c;   // within unit nq
                    bf[fn][kk] = *(const i32x4*)(Bs + buf * BSZ + nq * 16384 +
                                                 rowu * 128 +
                                                 (((kk * 4 + g) ^ (rowu & 7)) << 4));
                }
            asm volatile("s_waitcnt lgkmcnt(0)" ::: "memory");
            __builtin_amdgcn_sched_barrier(0);
            __builtin_amdgcn_s_setprio(1);
#pragma unroll
            for (int kk = 0; kk < 2; kk++)
#pragma unroll
                for (int fm = 0; fm < 4; fm++)
#pragma unroll
                    for (int fn = 0; fn < 2; fn++)
                        acc[fm][nq * 2 + fn] = __builtin_amdgcn_mfma_i32_16x16x64_i8(
                            af[fm][kk], bf[fn][kk], acc[fm][nq * 2 + fn], 0, 0, 0);
            __builtin_amdgcn_s_setprio(0);
        }
    }
#pragma unroll
    for (int fm = 0; fm < 4; fm++)
#pragma unroll
        for (int j = 0; j < 4; j++) {
            int row = bm * 128 + wr * 64 + fm * 16 + g * 4 + j;
            float sr = sa[row];
#pragma unroll
            for (int q = 0; q < 2 * NQ; q++) {
                int col = bn * BN + (q >> 1) * 128 + wc * 32 + (q & 1) * 16 + c;
                C[(size_t)row * N + col] = (float)acc[fm][q][j] * sr * sb[col];
            }
        }
}

// ---------------------------------------------------------------------------
// Merged post-GEMM kernel: blocks [0,256) = V int4 quant + transpose;
// blocks [256,..) = K int4-quant+RoPE waves then Q RoPE waves.
// ---------------------------------------------------------------------------
__global__ __launch_bounds__(256) void postq(
    const float* __restrict__ QKVf, const int* __restrict__ pos,
    unsigned short* __restrict__ Qbo, unsigned short* __restrict__ Kbo,
    unsigned short* __restrict__ Vbt)
{
    __shared__ unsigned short T[64][136];
    int bid = blockIdx.x;
    if (bid < 256) {                        // ---- V quant + transpose ----
        int t0 = (bid & 31) * 64;
        int kvh = bid >> 5;
        int tid = threadIdx.x;
        int r = tid >> 2, q4 = tid & 3;
        const float* gp = QKVf + (size_t)(t0 + r) * QKVN + (HID + KVD) + kvh * 128 + q4 * 32;
        float v[32];
#pragma unroll
        for (int i = 0; i < 8; i++) {
            float4 f = ((const float4*)gp)[i];
            v[4*i+0] = f.x; v[4*i+1] = f.y; v[4*i+2] = f.z; v[4*i+3] = f.w;
        }
        float mn = v[0], mx = v[0];
#pragma unroll
        for (int i = 1; i < 32; i++) { mn = fminf(mn, v[i]); mx = fmaxf(mx, v[i]); }
        mn = fminf(mn, __shfl_xor(mn, 1)); mx = fmaxf(mx, __shfl_xor(mx, 1));
        mn = fminf(mn, __shfl_xor(mn, 2)); mx = fmaxf(mx, __shfl_xor(mx, 2));
        float sc = fmaxf((mx - mn) / 15.0f, 1e-8f);
#pragma unroll
        for (int i = 0; i < 32; i++) {
            float q = fminf(fmaxf(rintf((v[i] - mn) / sc), 0.f), 15.f);
            T[r][q4 * 32 + i] = f2bf(q * sc + mn);
        }
        __syncthreads();
        int d = tid >> 1, hf = tid & 1;
#pragma unroll
        for (int b = 0; b < 4; b++) {
            us8 o;
#pragma unroll
            for (int j = 0; j < 8; j++) o[j] = T[hf * 32 + b * 8 + j][d];
            *(us8*)(Vbt + (size_t)(kvh * 128 + d) * SQ + t0 + hf * 32 + b * 8) = o;
        }
        return;
    }
    int wid = (bid - 256) * 4 + (threadIdx.x >> 6);
    int l = threadIdx.x & 63;
    float fr = exp2f(-(float)l * 0.3114307588956902f);   // log2(1e6)/64
    if (wid < SQ * NKVH) {                  // ---- K int4 quant + RoPE ----
        int t = wid >> 3, kvh = wid & 7;
        const float* gp = QKVf + (size_t)t * QKVN + HID + kvh * 128;
        float x1 = gp[l], x2 = gp[l + 64];
        float mn = fminf(x1, x2), mx = fmaxf(x1, x2);
#pragma unroll
        for (int o = 32; o >= 1; o >>= 1) {
            mn = fminf(mn, __shfl_xor(mn, o));
            mx = fmaxf(mx, __shfl_xor(mx, o));
        }
        float sc = fmaxf((mx - mn) / 15.0f, 1e-8f);
        float q1 = fminf(fmaxf(rintf((x1 - mn) / sc), 0.f), 15.f);
        float q2 = fminf(fmaxf(rintf((x2 - mn) / sc), 0.f), 15.f);
        x1 = q1 * sc + mn;
        x2 = q2 * sc + mn;
        float ang = (float)pos[t] * fr;
        float cs = cosf(ang), sn = sinf(ang);
        unsigned short* op = Kbo + (size_t)t * KVD + kvh * 128;
        op[l]      = f2bf(x1 * cs - x2 * sn);
        op[l + 64] = f2bf(x2 * cs + x1 * sn);
    } else {                                // ---- Q RoPE (pre-scaled) ----
        const float QSCL = (float)(0.08838834764831845 * 1.4426950408889634);
        int w2 = wid - SQ * NKVH;
        int t = w2 >> 5, h = w2 & 31;
        const float* gp = QKVf + (size_t)t * QKVN + h * 128;
        float x1 = gp[l], x2 = gp[l + 64];
        float ang = (float)pos[t] * fr;
        float cs = cosf(ang), sn = sinf(ang);
        unsigned short* op = Qbo + (size_t)t * HID + h * 128;
        op[l]      = f2bf((x1 * cs - x2 * sn) * QSCL);
        op[l + 64] = f2bf((x2 * cs + x1 * sn) * QSCL);
    }
}

// ---------------------------------------------------------------------------
// Causal GQA flash attention, swapped-operand MFMA, STRIP-PAIRED blocks with
// SPLIT loops (no runtime conditionals in hot bodies -> no spill).
// Block (h, j): strips j (A) and 31-j (B); loop 1 t=0..j runs BOTH groups
// (shared K/V fragment reads); A's output stored; loop 2 t=j+1..31-j runs B
// only.  Every block = exactly 33 MFMA group-steps.  K DMA double-buffered
// LDS; V^T reg-staged single-buffer.
// ---------------------------------------------------------------------------
__global__ __launch_bounds__(256, 2) void attn_kernel(
    const unsigned short* __restrict__ Qb, const unsigned short* __restrict__ Kb,
    const unsigned short* __restrict__ Vbt, float* __restrict__ AO)
{
    int h = blockIdx.x;
    int j = blockIdx.y;                            // strips j (A) and 31-j (B)
    int kvh = h >> 2;                              // NREP=4, consecutive repeat
    int tid = threadIdx.x;
    int l = tid & 63, w = tid >> 6;
    int g = l >> 4, c = l & 15;
    __shared__ unsigned short Ks[2 * 8192];        // 2 x (64 keys x 128 d), swz
    __shared__ unsigned short Vt[128 * 64];        // V^T tile, chunk^(row&7) swz
    __shared__ unsigned short Plds[4][2][16][72];  // per-wave P rows, 2 groups
    int rowA = j * 64 + w * 16 + c;                // group A q-row (strip j)
    int rowB = (31 - j) * 64 + w * 16 + c;         // group B q-row (strip 31-j)
    int NT = 32 - j;                               // kv tiles for group B

    auto stageK = [&](int buf, int kv0) {
#pragma unroll
        for (int i = 0; i < 4; i++) {
            int e = (i * 256 + tid) * 8;           // 0..8191
            int row = e >> 7, chunk = (e >> 3) & 15;
            gl2lds16(Kb + (size_t)(kv0 + row) * KVD + kvh * 128 + ((chunk ^ (row & 15)) << 3),
                     Ks + buf * 8192 + e);
        }
    };
    us8 vreg[4];
    auto stageV = [&](int kv0) {
#pragma unroll
        for (int i = 0; i < 4; i++) {
            int e = (i * 256 + tid) * 8;
            int r = e >> 6, cc = e & 63;
            vreg[i] = *(const us8*)(Vbt + (size_t)(kvh * 128 + r) * SQ + kv0 + cc);
        }
    };
    auto writeV = [&]() {
#pragma unroll
        for (int i = 0; i < 4; i++) {
            int e = (i * 256 + tid) * 8;
            int rv = e >> 6, chv = (e >> 3) & 7;
            *(us8*)(Vt + rv * 64 + ((chv ^ (rv & 7)) << 3)) = vreg[i];
        }
    };
    auto softmax = [&](f4v (&sf)[4], float& mrun, float& lrun, f4v (&acc)[8],
                       unsigned short* PW) {
        float pmax = sf[0][0];
#pragma unroll
        for (int n = 0; n < 4; n++)
#pragma unroll
            for (int jj = 0; jj < 4; jj++) pmax = fmaxf(pmax, sf[n][jj]);
        pmax = fmaxf(pmax, __shfl_xor(pmax, 16));
        pmax = fmaxf(pmax, __shfl_xor(pmax, 32));
        if (__any(pmax - mrun > 8.0f)) {           // defer-max (T13)
            float mnew = fmaxf(mrun, pmax);
            float alpha = exp2f(mrun - mnew);
            mrun = mnew;
            lrun *= alpha;
#pragma unroll
            for (int n = 0; n < 8; n++) acc[n] *= alpha;
        }
        float rsum = 0.f;
#pragma unroll
        for (int n = 0; n < 4; n++)
#pragma unroll
            for (int jj = 0; jj < 4; jj++) {
                float pv = exp2f(sf[n][jj] - mrun);
                sf[n][jj] = pv;
                rsum += pv;
            }
        rsum += __shfl_xor(rsum, 16);
        rsum += __shfl_xor(rsum, 32);
        lrun += rsum;
#pragma unroll
        for (int n = 0; n < 4; n++) {
            uint2 u;
            u.x = cvtpk_bf16(sf[n][0], sf[n][1]);
            u.y = cvtpk_bf16(sf[n][2], sf[n][3]);
            *(uint2*)(PW + c * 72 + n * 16 + g * 4) = u;
        }
    };

    stageK(0, 0);
    stageV(0);

    bh8 qfA[4], qfB[4];
    {
        const unsigned short* qa = Qb + (size_t)rowA * HID + h * 128;
        const unsigned short* qp = Qb + (size_t)rowB * HID + h * 128;
#pragma unroll
        for (int kk = 0; kk < 4; kk++) {
            qfA[kk] = *(const bh8*)(qa + kk * 32 + g * 8);
            qfB[kk] = *(const bh8*)(qp + kk * 32 + g * 8);
        }
    }
    writeV();
    asm volatile("s_waitcnt vmcnt(0)" ::: "memory");
    __syncthreads();

    float mrunB = -1e30f, lrunB = 0.f;
    f4v accB[8] = {};

    // -------- loop 1: t = 0..j, BOTH groups (r7's proven dual-group body) ----
    {
        float mrunA = -1e30f, lrunA = 0.f;
        f4v accA[8] = {};
        for (int t = 0; t <= j; t++) {
            int kv0 = t * 64;
            int buf = t & 1;
            stageK(buf ^ 1, kv0 + 64);             // t+1 <= j+1 < NT always
            stageV(kv0 + 64);
            f4v sfA[4], sfB[4];
            __builtin_amdgcn_s_setprio(1);
#pragma unroll
            for (int n = 0; n < 4; n++) {
                f4v aA = {}, aB = {};
                int rowk = n * 16 + c;
#pragma unroll
                for (int kk = 0; kk < 4; kk++) {
                    bh8 kf = *(const bh8*)(Ks + buf * 8192 + rowk * 128 +
                                           (((kk * 4 + g) ^ (rowk & 15)) << 3));
                    aA = __builtin_amdgcn_mfma_f32_16x16x32_bf16(kf, qfA[kk], aA, 0, 0, 0);
                    aB = __builtin_amdgcn_mfma_f32_16x16x32_bf16(kf, qfB[kk], aB, 0, 0, 0);
                }
                sfA[n] = aA; sfB[n] = aB;
            }
            __builtin_amdgcn_s_setprio(0);
            if (t == j) {                          // group A diagonal (uniform)
#pragma unroll
                for (int n = 0; n < 4; n++)
#pragma unroll
                    for (int jj = 0; jj < 4; jj++)
                        if (kv0 + n * 16 + g * 4 + jj > rowA) sfA[n][jj] = -1e30f;
            }
            softmax(sfA, mrunA, lrunA, accA, &Plds[w][0][0][0]);
            softmax(sfB, mrunB, lrunB, accB, &Plds[w][1][0][0]);
            __builtin_amdgcn_s_setprio(1);
#pragma unroll
            for (int kk = 0; kk < 2; kk++) {
                bh8 pbA = *(const bh8*)(&Plds[w][0][c][kk * 32 + g * 8]);
                bh8 pbB = *(const bh8*)(&Plds[w][1][c][kk * 32 + g * 8]);
#pragma unroll
                for (int n = 0; n < 8; n++) {
                    int rowv = n * 16 + c;
                    bh8 vf = *(const bh8*)(Vt + rowv * 64 + (((kk * 4 + g) ^ (rowv & 7)) << 3));
                    accA[n] = __builtin_amdgcn_mfma_f32_16x16x32_bf16(vf, pbA, accA[n], 0, 0, 0);
                    accB[n] = __builtin_amdgcn_mfma_f32_16x16x32_bf16(vf, pbB, accB[n], 0, 0, 0);
                }
            }
            __builtin_amdgcn_s_setprio(0);
            __syncthreads();                       // loop 2 always follows
            writeV();
            asm volatile("s_waitcnt vmcnt(0)" ::: "memory");
            __syncthreads();
        }
        // group A epilogue: accA dead afterwards -> loop 2 pressure drops
        float invA = 1.0f / lrunA;
#pragma unroll
        for (int n = 0; n < 8; n++) {
            f4v oA = accA[n] * invA;
            *(f4v*)(AO + (size_t)rowA * HID + h * 128 + n * 16 + g * 4) = oA;
        }
    }

    // -------- loop 2: t = j+1..NT-1, group B only ---------------------------
    for (int t = j + 1; t < NT; t++) {
        int kv0 = t * 64;
        int buf = t & 1;
        if (t + 1 < NT) { stageK(buf ^ 1, kv0 + 64); stageV(kv0 + 64); }
        f4v sfB[4];
        __builtin_amdgcn_s_setprio(1);
#pragma unroll
        for (int n = 0; n < 4; n++) {
            f4v aB = {};
            int rowk = n * 16 + c;
#pragma unroll
            for (int kk = 0; kk < 4; kk++) {
                bh8 kf = *(const bh8*)(Ks + buf * 8192 + rowk * 128 +
                                       (((kk * 4 + g) ^ (rowk & 15)) << 3));
                aB = __builtin_amdgcn_mfma_f32_16x16x32_bf16(kf, qfB[kk], aB, 0, 0, 0);
            }
            sfB[n] = aB;
        }
        __builtin_amdgcn_s_setprio(0);
        if (t == NT - 1) {                         // group B diagonal (uniform)
#pragma unroll
            for (int n = 0; n < 4; n++)
#pragma unroll
                for (int jj = 0; jj < 4; jj++)
                    if (kv0 + n * 16 + g * 4 + jj > rowB) sfB[n][jj] = -1e30f;
        }
        softmax(sfB, mrunB, lrunB, accB, &Plds[w][1][0][0]);
        __builtin_amdgcn_s_setprio(1);
#pragma unroll
        for (int kk = 0; kk < 2; kk++) {
            bh8 pbB = *(const bh8*)(&Plds[w][1][c][kk * 32 + g * 8]);
#pragma unroll
            for (int n = 0; n < 8; n++) {
                int rowv = n * 16 + c;
                bh8 vf = *(const bh8*)(Vt + rowv * 64 + (((kk * 4 + g) ^ (rowv & 7)) << 3));
                accB[n] = __builtin_amdgcn_mfma_f32_16x16x32_bf16(vf, pbB, accB[n], 0, 0, 0);
            }
        }
        __builtin_amdgcn_s_setprio(0);
        if (t + 1 < NT) {
            __syncthreads();
            writeV();
            asm volatile("s_waitcnt vmcnt(0)" ::: "memory");
            __syncthreads();
        }
    }
    float invB = 1.0f / lrunB;
#pragma unroll
    for (int n = 0; n < 8; n++) {
        f4v oB = accB[n] * invB;
        *(f4v*)(AO + (size_t)rowB * HID + h * 128 + n * 16 + g * 4) = oB;
    }
}

// ---------------------------------------------------------------------------
extern "C" void kernel_launch(void* const* d_in, const int* in_sizes, int n_in,
                              void* d_out, int out_size, void* d_ws, size_t ws_size,
                              hipStream_t stream)
{
    const float* x   = (const float*)d_in[0];
    const int*   pos = (const int*)d_in[1];
    const float* rw  = (const float*)d_in[2];
    const float* Wq  = (const float*)d_in[3];
    const float* Wk  = (const float*)d_in[4];
    const float* Wv  = (const float*)d_in[5];
    const float* Wo  = (const float*)d_in[6];
    float* out = (float*)d_out;

    char* p = (char*)d_ws;
    auto alloc = [&](size_t bytes) -> void* {
        void* r = (void*)p;
        p += (bytes + 255) & ~(size_t)255;
        return r;
    };
    char*           xq    = (char*)alloc((size_t)SQ * HID);
    float*          sx    = (float*)alloc(SQ * 4);
    char*           wqkv  = (char*)alloc((size_t)QKVN * HID);
    char*           woq   = (char*)alloc((size_t)HID * HID);
    float*          swqkv = (float*)alloc(QKVN * 4);
    float*          swo   = (float*)alloc(HID * 4);
    float*          QKVf  = (float*)alloc((size_t)SQ * QKVN * 4);  // reused: AO, attq
    unsigned short* Qb    = (unsigned short*)alloc((size_t)SQ * HID * 2);
    unsigned short* Kb    = (unsigned short*)alloc((size_t)SQ * KVD * 2);
    unsigned short* Vbt   = (unsigned short*)alloc((size_t)SQ * KVD * 2);
    float*          sa    = (float*)alloc(SQ * 4);

    size_t need = (size_t)(p - (char*)d_ws);
    if (ws_size < need) {
        // sentinel: absmax ~3.4e38 tells us ws was too small
        hipMemsetAsync(d_out, 0x7f, 4, stream);
        return;
    }
    float*          AO   = QKVf;                                   // QKV consumed before attn
    char*           attq = (char*)(QKVf + (size_t)SQ * HID);
    // 1) weights + rmsnorm'd hidden states int8-quantized in one dispatch
    prequant<<<QKVN + HID + SQ, 256, 0, stream>>>(
        Wq, Wk, Wv, Wo, x, rw, wqkv, woq, xq, swqkv, swo, sx);
    // 2) merged QKV projection: EXACT i8 MFMA; BM=128 BN=384 -> 256 blocks
    gemm128i8<384><<<dim3((SQ / 128) * (QKVN / 384)), 512, 0, stream>>>(
        xq, wqkv, sx, swqkv, QKVf, SQ, QKVN, HID, SQ / 128);
    // 3) V quant+transpose, K quant+RoPE, Q RoPE in one dispatch
    postq<<<256 + (SQ * NKVH + SQ * NHEAD) / 4, 256, 0, stream>>>(
        QKVf, pos, Qb, Kb, Vbt);
    // 4) causal GQA flash attention (strip-paired, split loops)
    attn_kernel<<<dim3(NHEAD, 16), 256, 0, stream>>>(Qb, Kb, Vbt, AO);
    // 5) per-token int8 quant of attention output + O projection
    rowquant_kernel<<<SQ, 256, 0, stream>>>(AO, attq, sa);
    gemm128i8<256><<<dim3((SQ / 128) * (HID / 256)), 512, 0, stream>>>(
        attq, woq, sa, swo, out, SQ, HID, HID, SQ / 128);
}

// Round 10
// 239.699 us; speedup vs baseline: 9.5392x; 1.0179x over previous
//
#include <hip/hip_runtime.h>

// ---------------------------------------------------------------------------
// QMixtralAttention: rmsnorm -> int8 quant -> QKV proj (EXACT i8 MFMA i32-acc,
// merged N=6144, BK=128 counted-vmcnt schedule) -> int4 KV quant -> RoPE ->
// causal GQA flash attention (swapped-operand bf16 MFMA, strip-paired blocks,
// SPLIT loops) -> int8 -> O proj.  Quant kernels use hoisted reciprocal.
// ---------------------------------------------------------------------------

#define SQ   2048
#define HID  4096
#define NHEAD 32
#define HDIM 128
#define NKVH 8
#define KVD  1024   // NKVH*HDIM
#define QKVN 6144   // HID + 2*KVD

typedef __attribute__((ext_vector_type(8))) short          bh8;   // 8 x bf16 bits
typedef __attribute__((ext_vector_type(8))) unsigned short us8;
typedef __attribute__((ext_vector_type(4))) float          f4v;
typedef __attribute__((ext_vector_type(4))) int            i32x4; // i8 MFMA A/B/C

__device__ __forceinline__ unsigned short f2bf(float f) {
    unsigned u = __float_as_uint(f);
    u += 0x7fffu + ((u >> 16) & 1u);          // RNE
    return (unsigned short)(u >> 16);
}

__device__ __forceinline__ unsigned cvtpk_bf16(float a, float b) {
    unsigned r;
    asm("v_cvt_pk_bf16_f32 %0, %1, %2" : "=v"(r) : "v"(a), "v"(b));
    return r;
}

// async global -> LDS, 16B per lane (m97 pattern)
__device__ __forceinline__ void gl2lds16(const void* g, void* l) {
    __builtin_amdgcn_global_load_lds(
        (const __attribute__((address_space(1))) unsigned int*)g,
        (__attribute__((address_space(3))) unsigned int*)l, 16, 0, 0);
}

template<int N> __device__ __forceinline__ void vmc() {
    if constexpr (N == 0) asm volatile("s_waitcnt vmcnt(0)" ::: "memory");
    else if constexpr (N == 2) asm volatile("s_waitcnt vmcnt(2)" ::: "memory");
    else if constexpr (N == 4) asm volatile("s_waitcnt vmcnt(4)" ::: "memory");
    else if constexpr (N == 6) asm volatile("s_waitcnt vmcnt(6)" ::: "memory");
    else if constexpr (N == 8) asm volatile("s_waitcnt vmcnt(8)" ::: "memory");
}

// ---------------------------------------------------------------------------
// Shared per-row (4096-wide) symmetric int8 quant body -> packed int8 + scale.
// Hoisted reciprocal: ONE division per row, 16 multiplies per thread
// (v*(1/s) vs v/s: <=1-2 ulp -> rint flip prob ~1e-7/elem, impact ~2e-3).
// ---------------------------------------------------------------------------
__device__ __forceinline__ void rq_body(float v[16],
                                        char* __restrict__ dst,
                                        float* __restrict__ sout,
                                        float* red, int tid, int l, int wv)
{
    float am = 0.f;
#pragma unroll
    for (int i = 0; i < 16; i++) am = fmaxf(am, fabsf(v[i]));
#pragma unroll
    for (int o = 32; o >= 1; o >>= 1) am = fmaxf(am, __shfl_xor(am, o));
    if (l == 0) red[wv] = am;
    __syncthreads();
    am = fmaxf(fmaxf(red[0], red[1]), fmaxf(red[2], red[3]));
    float s = fmaxf(am / 127.0f, 1e-8f);
    float inv = 1.0f / s;                          // hoisted reciprocal
    if (tid == 0) *sout = s;
#pragma unroll
    for (int i = 0; i < 4; i++) {
        unsigned pk = 0;
#pragma unroll
        for (int j = 0; j < 4; j++) {
            float q = rintf(v[4*i+j] * inv);
            q = fminf(fmaxf(q, -127.f), 127.f);
            pk |= ((unsigned)((int)q & 0xff)) << (8 * j);
        }
        ((unsigned*)dst)[i * 256 + tid] = pk;      // bytes i*1024 + tid*4
    }
}

// All 4 weight matrices (10240 rows) + rmsnorm'd hidden states (2048 rows)
// int8-quantized in ONE dispatch.
__global__ __launch_bounds__(256) void prequant(
    const float* __restrict__ Wq, const float* __restrict__ Wk,
    const float* __restrict__ Wv, const float* __restrict__ Wo,
    const float* __restrict__ X, const float* __restrict__ rw,
    char* __restrict__ wqkv, char* __restrict__ woq, char* __restrict__ xq,
    float* __restrict__ swqkv, float* __restrict__ swo, float* __restrict__ sx)
{
    int row = blockIdx.x;
    int tid = threadIdx.x;
    int l = tid & 63, wv = tid >> 6;
    const float* src; char* dst; float* sout; bool dorms = false;
    if (row < HID)            { src = Wq + (size_t)row * HID;                 dst = wqkv + (size_t)row * HID; sout = swqkv + row; }
    else if (row < HID + KVD) { src = Wk + (size_t)(row - HID) * HID;         dst = wqkv + (size_t)row * HID; sout = swqkv + row; }
    else if (row < QKVN)      { src = Wv + (size_t)(row - HID - KVD) * HID;   dst = wqkv + (size_t)row * HID; sout = swqkv + row; }
    else if (row < QKVN+HID)  { int r = row - QKVN; src = Wo + (size_t)r * HID; dst = woq + (size_t)r * HID;  sout = swo + r; }
    else { int r = row - QKVN - HID; src = X + (size_t)r * HID; dst = xq + (size_t)r * HID; sout = sx + r; dorms = true; }
    float v[16];
#pragma unroll
    for (int i = 0; i < 4; i++) {
        float4 f = ((const float4*)src)[i * 256 + tid];
        v[4*i+0] = f.x; v[4*i+1] = f.y; v[4*i+2] = f.z; v[4*i+3] = f.w;
    }
    __shared__ float red[4];
    if (dorms) {
        float ss = 0.f;
#pragma unroll
        for (int i = 0; i < 16; i++) ss += v[i] * v[i];
#pragma unroll
        for (int o = 32; o >= 1; o >>= 1) ss += __shfl_xor(ss, o);
        if (l == 0) red[wv] = ss;
        __syncthreads();
        float tot = red[0] + red[1] + red[2] + red[3];
        float rs = rsqrtf(tot * (1.0f / 4096.0f) + 1e-5f);
        __syncthreads();   // red reused below
#pragma unroll
        for (int i = 0; i < 4; i++) {
            float4 wf = ((const float4*)rw)[i * 256 + tid];
            v[4*i+0] = v[4*i+0] * rs * wf.x;
            v[4*i+1] = v[4*i+1] * rs * wf.y;
            v[4*i+2] = v[4*i+2] * rs * wf.z;
            v[4*i+3] = v[4*i+3] * rs * wf.w;
        }
    }
    rq_body(v, dst, sout, red, tid, l, wv);
}

// Per-row int8 quant, no rms (attn output)
__global__ __launch_bounds__(256) void rowquant_kernel(
    const float* __restrict__ X, char* __restrict__ Q, float* __restrict__ Sout)
{
    int row = blockIdx.x;
    int tid = threadIdx.x;
    int l = tid & 63, wv = tid >> 6;
    const float* xr = X + (size_t)row * 4096;
    float v[16];
#pragma unroll
    for (int i = 0; i < 4; i++) {
        float4 f = ((const float4*)xr)[i * 256 + tid];
        v[4*i+0] = f.x; v[4*i+1] = f.y; v[4*i+2] = f.z; v[4*i+3] = f.w;
    }
    __shared__ float red[4];
    rq_body(v, Q + (size_t)row * 4096, Sout + row, red, tid, l, wv);
}

// ---------------------------------------------------------------------------
// int8 GEMM (EXACT i32 accum): C[m][n] = sa[m]*sb[n] * sum_k A[m][k]*B[n][k].
// mfma_i32_16x16x64_i8, BM=128 x BN (384/256), BK=128, 8 waves (2M x 4N).
// Grid = exactly 256 blocks.  Counted-vmcnt phase schedule (unchanged r6).
// ---------------------------------------------------------------------------
template<int BN>
__global__ __launch_bounds__(512, 1) void gemm128i8(
    const char* __restrict__ A, const char* __restrict__ B,
    const float* __restrict__ sa, const float* __restrict__ sb,
    float* __restrict__ C, int M, int N, int K, int NBM)
{
    constexpr int NQ  = BN / 128;
    constexpr int BSZ = BN * 128;              // bytes per B buffer
    __shared__ char As[2 * 16384];             // 2 buf x 128 rows x 128 B
    __shared__ char Bs[2 * BSZ];
    int tid = threadIdx.x;
    int l = tid & 63, wid = tid >> 6;
    int wr = wid >> 2, wc = wid & 3;           // 2M x 4N waves
    int g = l >> 4, c = l & 15;
    int wg = blockIdx.x;
    int cpx = (int)gridDim.x >> 3;             // grid == 256, multiple of 8
    int swz = (wg & 7) * cpx + (wg >> 3);
    int bm = swz % NBM, bn = swz / NBM;
    const char* Ab = A + (size_t)bm * 128 * K;
    const char* Bb = B + (size_t)bn * BN * K;

    auto stageA = [&](int buf, int tt) {
#pragma unroll
        for (int r = 0; r < 2; r++) {
            int e = (r * 512 + tid) * 16;      // 0..16383
            int row = e >> 7, chunk = (e >> 4) & 7;
            gl2lds16(Ab + (size_t)row * K + tt * 128 + ((chunk ^ (row & 7)) << 4),
                     As + buf * 16384 + e);
        }
    };
    auto stageB = [&](int buf, int u, int tt) {
#pragma unroll
        for (int r = 0; r < 2; r++) {
            int e = (r * 512 + tid) * 16;
            int row = e >> 7, chunk = (e >> 4) & 7;
            gl2lds16(Bb + (size_t)(u * 128 + row) * K + tt * 128 + ((chunk ^ (row & 7)) << 4),
                     Bs + buf * BSZ + u * 16384 + e);
        }
    };
    i32x4 af[4][2];
    auto LDA = [&](int buf) {
#pragma unroll
        for (int fm = 0; fm < 4; fm++)
#pragma unroll
            for (int kk = 0; kk < 2; kk++) {
                int row = wr * 64 + fm * 16 + c;
                af[fm][kk] = *(const i32x4*)(As + buf * 16384 + row * 128 +
                                             (((kk * 4 + g) ^ (row & 7)) << 4));
            }
    };

    stageA(0, 0);
#pragma unroll
    for (int u = 0; u < NQ; u++) stageB(0, u, 0);

    i32x4 acc[4][2 * NQ] = {};
    int nt = K >> 7;
    for (int t = 0; t < nt; t++) {
        int buf = t & 1;
        bool last = (t == nt - 1);
#pragma unroll
        for (int nq = 0; nq < NQ; nq++) {
            if (last) { if (nq == 0) vmc<0>(); }
            else if (nq == 0) vmc<2 * (NQ - 1)>();
            else vmc<2 * NQ>();
            asm volatile("s_barrier" ::: "memory");
            if (!last) {
                if (nq == 0) { stageA(buf ^ 1, t + 1); stageB(buf ^ 1, 0, t + 1); }
                else stageB(buf ^ 1, nq, t + 1);
            }
            if (nq == 0) LDA(buf);
            i32x4 bf[2][2];
#pragma unroll
            for (int fn = 0; fn < 2; fn++)
#pragma unroll
                for (int kk = 0; kk < 2; kk++) {
                    int rowu = wc * 32 + fn * 16 + c;   // within unit nq
                    bf[fn][kk] = *(const i32x4*)(Bs + buf * BSZ + nq * 16384 +
                                                 rowu * 128 +
                                                 (((kk * 4 + g) ^ (rowu & 7)) << 4));
                }
            asm volatile("s_waitcnt lgkmcnt(0)" ::: "memory");
            __builtin_amdgcn_sched_barrier(0);
            __builtin_amdgcn_s_setprio(1);
#pragma unroll
            for (int kk = 0; kk < 2; kk++)
#pragma unroll
                for (int fm = 0; fm < 4; fm++)
#pragma unroll
                    for (int fn = 0; fn < 2; fn++)
                        acc[fm][nq * 2 + fn] = __builtin_amdgcn_mfma_i32_16x16x64_i8(
                            af[fm][kk], bf[fn][kk], acc[fm][nq * 2 + fn], 0, 0, 0);
            __builtin_amdgcn_s_setprio(0);
        }
    }
#pragma unroll
    for (int fm = 0; fm < 4; fm++)
#pragma unroll
        for (int j = 0; j < 4; j++) {
            int row = bm * 128 + wr * 64 + fm * 16 + g * 4 + j;
            float sr = sa[row];
#pragma unroll
            for (int q = 0; q < 2 * NQ; q++) {
                int col = bn * BN + (q >> 1) * 128 + wc * 32 + (q & 1) * 16 + c;
                C[(size_t)row * N + col] = (float)acc[fm][q][j] * sr * sb[col];
            }
        }
}

// ---------------------------------------------------------------------------
// Merged post-GEMM kernel: blocks [0,256) = V int4 quant + transpose;
// blocks [256,..) = K int4-quant+RoPE waves then Q RoPE waves.
// ---------------------------------------------------------------------------
__global__ __launch_bounds__(256) void postq(
    const float* __restrict__ QKVf, const int* __restrict__ pos,
    unsigned short* __restrict__ Qbo, unsigned short* __restrict__ Kbo,
    unsigned short* __restrict__ Vbt)
{
    __shared__ unsigned short T[64][136];
    int bid = blockIdx.x;
    if (bid < 256) {                        // ---- V quant + transpose ----
        int t0 = (bid & 31) * 64;
        int kvh = bid >> 5;
        int tid = threadIdx.x;
        int r = tid >> 2, q4 = tid & 3;
        const float* gp = QKVf + (size_t)(t0 + r) * QKVN + (HID + KVD) + kvh * 128 + q4 * 32;
        float v[32];
#pragma unroll
        for (int i = 0; i < 8; i++) {
            float4 f = ((const float4*)gp)[i];
            v[4*i+0] = f.x; v[4*i+1] = f.y; v[4*i+2] = f.z; v[4*i+3] = f.w;
        }
        float mn = v[0], mx = v[0];
#pragma unroll
        for (int i = 1; i < 32; i++) { mn = fminf(mn, v[i]); mx = fmaxf(mx, v[i]); }
        mn = fminf(mn, __shfl_xor(mn, 1)); mx = fmaxf(mx, __shfl_xor(mx, 1));
        mn = fminf(mn, __shfl_xor(mn, 2)); mx = fmaxf(mx, __shfl_xor(mx, 2));
        float sc = fmaxf((mx - mn) / 15.0f, 1e-8f);
#pragma unroll
        for (int i = 0; i < 32; i++) {
            float q = fminf(fmaxf(rintf((v[i] - mn) / sc), 0.f), 15.f);
            T[r][q4 * 32 + i] = f2bf(q * sc + mn);
        }
        __syncthreads();
        int d = tid >> 1, hf = tid & 1;
#pragma unroll
        for (int b = 0; b < 4; b++) {
            us8 o;
#pragma unroll
            for (int j = 0; j < 8; j++) o[j] = T[hf * 32 + b * 8 + j][d];
            *(us8*)(Vbt + (size_t)(kvh * 128 + d) * SQ + t0 + hf * 32 + b * 8) = o;
        }
        return;
    }
    int wid = (bid - 256) * 4 + (threadIdx.x >> 6);
    int l = threadIdx.x & 63;
    float fr = exp2f(-(float)l * 0.3114307588956902f);   // log2(1e6)/64
    if (wid < SQ * NKVH) {                  // ---- K int4 quant + RoPE ----
        int t = wid >> 3, kvh = wid & 7;
        const float* gp = QKVf + (size_t)t * QKVN + HID + kvh * 128;
        float x1 = gp[l], x2 = gp[l + 64];
        float mn = fminf(x1, x2), mx = fmaxf(x1, x2);
#pragma unroll
        for (int o = 32; o >= 1; o >>= 1) {
            mn = fminf(mn, __shfl_xor(mn, o));
            mx = fmaxf(mx, __shfl_xor(mx, o));
        }
        float sc = fmaxf((mx - mn) / 15.0f, 1e-8f);
        float q1 = fminf(fmaxf(rintf((x1 - mn) / sc), 0.f), 15.f);
        float q2 = fminf(fmaxf(rintf((x2 - mn) / sc), 0.f), 15.f);
        x1 = q1 * sc + mn;
        x2 = q2 * sc + mn;
        float ang = (float)pos[t] * fr;
        float cs = cosf(ang), sn = sinf(ang);
        unsigned short* op = Kbo + (size_t)t * KVD + kvh * 128;
        op[l]      = f2bf(x1 * cs - x2 * sn);
        op[l + 64] = f2bf(x2 * cs + x1 * sn);
    } else {                                // ---- Q RoPE (pre-scaled) ----
        const float QSCL = (float)(0.08838834764831845 * 1.4426950408889634);
        int w2 = wid - SQ * NKVH;
        int t = w2 >> 5, h = w2 & 31;
        const float* gp = QKVf + (size_t)t * QKVN + h * 128;
        float x1 = gp[l], x2 = gp[l + 64];
        float ang = (float)pos[t] * fr;
        float cs = cosf(ang), sn = sinf(ang);
        unsigned short* op = Qbo + (size_t)t * HID + h * 128;
        op[l]      = f2bf((x1 * cs - x2 * sn) * QSCL);
        op[l + 64] = f2bf((x2 * cs + x1 * sn) * QSCL);
    }
}

// ---------------------------------------------------------------------------
// Causal GQA flash attention, swapped-operand MFMA, STRIP-PAIRED blocks with
// SPLIT loops (no runtime conditionals in hot bodies -> no spill).
// Block (h, j): strips j (A) and 31-j (B); loop 1 t=0..j runs BOTH groups
// (shared K/V fragment reads); A's output stored; loop 2 t=j+1..31-j runs B
// only.  Every block = exactly 33 MFMA group-steps.  K DMA double-buffered
// LDS; V^T reg-staged single-buffer.
// ---------------------------------------------------------------------------
__global__ __launch_bounds__(256, 2) void attn_kernel(
    const unsigned short* __restrict__ Qb, const unsigned short* __restrict__ Kb,
    const unsigned short* __restrict__ Vbt, float* __restrict__ AO)
{
    int h = blockIdx.x;
    int j = blockIdx.y;                            // strips j (A) and 31-j (B)
    int kvh = h >> 2;                              // NREP=4, consecutive repeat
    int tid = threadIdx.x;
    int l = tid & 63, w = tid >> 6;
    int g = l >> 4, c = l & 15;
    __shared__ unsigned short Ks[2 * 8192];        // 2 x (64 keys x 128 d), swz
    __shared__ unsigned short Vt[128 * 64];        // V^T tile, chunk^(row&7) swz
    __shared__ unsigned short Plds[4][2][16][72];  // per-wave P rows, 2 groups
    int rowA = j * 64 + w * 16 + c;                // group A q-row (strip j)
    int rowB = (31 - j) * 64 + w * 16 + c;         // group B q-row (strip 31-j)
    int NT = 32 - j;                               // kv tiles for group B

    auto stageK = [&](int buf, int kv0) {
#pragma unroll
        for (int i = 0; i < 4; i++) {
            int e = (i * 256 + tid) * 8;           // 0..8191
            int row = e >> 7, chunk = (e >> 3) & 15;
            gl2lds16(Kb + (size_t)(kv0 + row) * KVD + kvh * 128 + ((chunk ^ (row & 15)) << 3),
                     Ks + buf * 8192 + e);
        }
    };
    us8 vreg[4];
    auto stageV = [&](int kv0) {
#pragma unroll
        for (int i = 0; i < 4; i++) {
            int e = (i * 256 + tid) * 8;
            int r = e >> 6, cc = e & 63;
            vreg[i] = *(const us8*)(Vbt + (size_t)(kvh * 128 + r) * SQ + kv0 + cc);
        }
    };
    auto writeV = [&]() {
#pragma unroll
        for (int i = 0; i < 4; i++) {
            int e = (i * 256 + tid) * 8;
            int rv = e >> 6, chv = (e >> 3) & 7;
            *(us8*)(Vt + rv * 64 + ((chv ^ (rv & 7)) << 3)) = vreg[i];
        }
    };
    auto softmax = [&](f4v (&sf)[4], float& mrun, float& lrun, f4v (&acc)[8],
                       unsigned short* PW) {
        float pmax = sf[0][0];
#pragma unroll
        for (int n = 0; n < 4; n++)
#pragma unroll
            for (int jj = 0; jj < 4; jj++) pmax = fmaxf(pmax, sf[n][jj]);
        pmax = fmaxf(pmax, __shfl_xor(pmax, 16));
        pmax = fmaxf(pmax, __shfl_xor(pmax, 32));
        if (__any(pmax - mrun > 8.0f)) {           // defer-max (T13)
            float mnew = fmaxf(mrun, pmax);
            float alpha = exp2f(mrun - mnew);
            mrun = mnew;
            lrun *= alpha;
#pragma unroll
            for (int n = 0; n < 8; n++) acc[n] *= alpha;
        }
        float rsum = 0.f;
#pragma unroll
        for (int n = 0; n < 4; n++)
#pragma unroll
            for (int jj = 0; jj < 4; jj++) {
                float pv = exp2f(sf[n][jj] - mrun);
                sf[n][jj] = pv;
                rsum += pv;
            }
        rsum += __shfl_xor(rsum, 16);
        rsum += __shfl_xor(rsum, 32);
        lrun += rsum;
#pragma unroll
        for (int n = 0; n < 4; n++) {
            uint2 u;
            u.x = cvtpk_bf16(sf[n][0], sf[n][1]);
            u.y = cvtpk_bf16(sf[n][2], sf[n][3]);
            *(uint2*)(PW + c * 72 + n * 16 + g * 4) = u;
        }
    };

    stageK(0, 0);
    stageV(0);

    bh8 qfA[4], qfB[4];
    {
        const unsigned short* qa = Qb + (size_t)rowA * HID + h * 128;
        const unsigned short* qp = Qb + (size_t)rowB * HID + h * 128;
#pragma unroll
        for (int kk = 0; kk < 4; kk++) {
            qfA[kk] = *(const bh8*)(qa + kk * 32 + g * 8);
            qfB[kk] = *(const bh8*)(qp + kk * 32 + g * 8);
        }
    }
    writeV();
    asm volatile("s_waitcnt vmcnt(0)" ::: "memory");
    __syncthreads();

    float mrunB = -1e30f, lrunB = 0.f;
    f4v accB[8] = {};

    // -------- loop 1: t = 0..j, BOTH groups (r7's proven dual-group body) ----
    {
        float mrunA = -1e30f, lrunA = 0.f;
        f4v accA[8] = {};
        for (int t = 0; t <= j; t++) {
            int kv0 = t * 64;
            int buf = t & 1;
            stageK(buf ^ 1, kv0 + 64);             // t+1 <= j+1 < NT always
            stageV(kv0 + 64);
            f4v sfA[4], sfB[4];
            __builtin_amdgcn_s_setprio(1);
#pragma unroll
            for (int n = 0; n < 4; n++) {
                f4v aA = {}, aB = {};
                int rowk = n * 16 + c;
#pragma unroll
                for (int kk = 0; kk < 4; kk++) {
                    bh8 kf = *(const bh8*)(Ks + buf * 8192 + rowk * 128 +
                                           (((kk * 4 + g) ^ (rowk & 15)) << 3));
                    aA = __builtin_amdgcn_mfma_f32_16x16x32_bf16(kf, qfA[kk], aA, 0, 0, 0);
                    aB = __builtin_amdgcn_mfma_f32_16x16x32_bf16(kf, qfB[kk], aB, 0, 0, 0);
                }
                sfA[n] = aA; sfB[n] = aB;
            }
            __builtin_amdgcn_s_setprio(0);
            if (t == j) {                          // group A diagonal (uniform)
#pragma unroll
                for (int n = 0; n < 4; n++)
#pragma unroll
                    for (int jj = 0; jj < 4; jj++)
                        if (kv0 + n * 16 + g * 4 + jj > rowA) sfA[n][jj] = -1e30f;
            }
            softmax(sfA, mrunA, lrunA, accA, &Plds[w][0][0][0]);
            softmax(sfB, mrunB, lrunB, accB, &Plds[w][1][0][0]);
            __builtin_amdgcn_s_setprio(1);
#pragma unroll
            for (int kk = 0; kk < 2; kk++) {
                bh8 pbA = *(const bh8*)(&Plds[w][0][c][kk * 32 + g * 8]);
                bh8 pbB = *(const bh8*)(&Plds[w][1][c][kk * 32 + g * 8]);
#pragma unroll
                for (int n = 0; n < 8; n++) {
                    int rowv = n * 16 + c;
                    bh8 vf = *(const bh8*)(Vt + rowv * 64 + (((kk * 4 + g) ^ (rowv & 7)) << 3));
                    accA[n] = __builtin_amdgcn_mfma_f32_16x16x32_bf16(vf, pbA, accA[n], 0, 0, 0);
                    accB[n] = __builtin_amdgcn_mfma_f32_16x16x32_bf16(vf, pbB, accB[n], 0, 0, 0);
                }
            }
            __builtin_amdgcn_s_setprio(0);
            __syncthreads();                       // loop 2 always follows
            writeV();
            asm volatile("s_waitcnt vmcnt(0)" ::: "memory");
            __syncthreads();
        }
        // group A epilogue: accA dead afterwards -> loop 2 pressure drops
        float invA = 1.0f / lrunA;
#pragma unroll
        for (int n = 0; n < 8; n++) {
            f4v oA = accA[n] * invA;
            *(f4v*)(AO + (size_t)rowA * HID + h * 128 + n * 16 + g * 4) = oA;
        }
    }

    // -------- loop 2: t = j+1..NT-1, group B only ---------------------------
    for (int t = j + 1; t < NT; t++) {
        int kv0 = t * 64;
        int buf = t & 1;
        if (t + 1 < NT) { stageK(buf ^ 1, kv0 + 64); stageV(kv0 + 64); }
        f4v sfB[4];
        __builtin_amdgcn_s_setprio(1);
#pragma unroll
        for (int n = 0; n < 4; n++) {
            f4v aB = {};
            int rowk = n * 16 + c;
#pragma unroll
            for (int kk = 0; kk < 4; kk++) {
                bh8 kf = *(const bh8*)(Ks + buf * 8192 + rowk * 128 +
                                       (((kk * 4 + g) ^ (rowk & 15)) << 3));
                aB = __builtin_amdgcn_mfma_f32_16x16x32_bf16(kf, qfB[kk], aB, 0, 0, 0);
            }
            sfB[n] = aB;
        }
        __builtin_amdgcn_s_setprio(0);
        if (t == NT - 1) {                         // group B diagonal (uniform)
#pragma unroll
            for (int n = 0; n < 4; n++)
#pragma unroll
                for (int jj = 0; jj < 4; jj++)
                    if (kv0 + n * 16 + g * 4 + jj > rowB) sfB[n][jj] = -1e30f;
        }
        softmax(sfB, mrunB, lrunB, accB, &Plds[w][1][0][0]);
        __builtin_amdgcn_s_setprio(1);
#pragma unroll
        for (int kk = 0; kk < 2; kk++) {
            bh8 pbB = *(const bh8*)(&Plds[w][1][c][kk * 32 + g * 8]);
#pragma unroll
            for (int n = 0; n < 8; n++) {
                int rowv = n * 16 + c;
                bh8 vf = *(const bh8*)(Vt + rowv * 64 + (((kk * 4 + g) ^ (rowv & 7)) << 3));
                accB[n] = __builtin_amdgcn_mfma_f32_16x16x32_bf16(vf, pbB, accB[n], 0, 0, 0);
            }
        }
        __builtin_amdgcn_s_setprio(0);
        if (t + 1 < NT) {
            __syncthreads();
            writeV();
            asm volatile("s_waitcnt vmcnt(0)" ::: "memory");
            __syncthreads();
        }
    }
    float invB = 1.0f / lrunB;
#pragma unroll
    for (int n = 0; n < 8; n++) {
        f4v oB = accB[n] * invB;
        *(f4v*)(AO + (size_t)rowB * HID + h * 128 + n * 16 + g * 4) = oB;
    }
}

// ---------------------------------------------------------------------------
extern "C" void kernel_launch(void* const* d_in, const int* in_sizes, int n_in,
                              void* d_out, int out_size, void* d_ws, size_t ws_size,
                              hipStream_t stream)
{
    const float* x   = (const float*)d_in[0];
    const int*   pos = (const int*)d_in[1];
    const float* rw  = (const float*)d_in[2];
    const float* Wq  = (const float*)d_in[3];
    const float* Wk  = (const float*)d_in[4];
    const float* Wv  = (const float*)d_in[5];
    const float* Wo  = (const float*)d_in[6];
    float* out = (float*)d_out;

    char* p = (char*)d_ws;
    auto alloc = [&](size_t bytes) -> void* {
        void* r = (void*)p;
        p += (bytes + 255) & ~(size_t)255;
        return r;
    };
    char*           xq    = (char*)alloc((size_t)SQ * HID);
    float*          sx    = (float*)alloc(SQ * 4);
    char*           wqkv  = (char*)alloc((size_t)QKVN * HID);
    char*           woq   = (char*)alloc((size_t)HID * HID);
    float*          swqkv = (float*)alloc(QKVN * 4);
    float*          swo   = (float*)alloc(HID * 4);
    float*          QKVf  = (float*)alloc((size_t)SQ * QKVN * 4);  // reused: AO, attq
    unsigned short* Qb    = (unsigned short*)alloc((size_t)SQ * HID * 2);
    unsigned short* Kb    = (unsigned short*)alloc((size_t)SQ * KVD * 2);
    unsigned short* Vbt   = (unsigned short*)alloc((size_t)SQ * KVD * 2);
    float*          sa    = (float*)alloc(SQ * 4);

    size_t need = (size_t)(p - (char*)d_ws);
    if (ws_size < need) {
        // sentinel: absmax ~3.4e38 tells us ws was too small
        hipMemsetAsync(d_out, 0x7f, 4, stream);
        return;
    }
    float*          AO   = QKVf;                                   // QKV consumed before attn
    char*           attq = (char*)(QKVf + (size_t)SQ * HID);
    // 1) weights + rmsnorm'd hidden states int8-quantized in one dispatch
    prequant<<<QKVN + HID + SQ, 256, 0, stream>>>(
        Wq, Wk, Wv, Wo, x, rw, wqkv, woq, xq, swqkv, swo, sx);
    // 2) merged QKV projection: EXACT i8 MFMA; BM=128 BN=384 -> 256 blocks
    gemm128i8<384><<<dim3((SQ / 128) * (QKVN / 384)), 512, 0, stream>>>(
        xq, wqkv, sx, swqkv, QKVf, SQ, QKVN, HID, SQ / 128);
    // 3) V quant+transpose, K quant+RoPE, Q RoPE in one dispatch
    postq<<<256 + (SQ * NKVH + SQ * NHEAD) / 4, 256, 0, stream>>>(
        QKVf, pos, Qb, Kb, Vbt);
    // 4) causal GQA flash attention (strip-paired, split loops)
    attn_kernel<<<dim3(NHEAD, 16), 256, 0, stream>>>(Qb, Kb, Vbt, AO);
    // 5) per-token int8 quant of attention output + O projection
    rowquant_kernel<<<SQ, 256, 0, stream>>>(AO, attq, sa);
    gemm128i8<256><<<dim3((SQ / 128) * (HID / 256)), 512, 0, stream>>>(
        attq, woq, sa, swo, out, SQ, HID, HID, SQ / 128);
}